// Round 8
// baseline (88.713 us; speedup 1.0000x reference)
//
#include <hip/hip_runtime.h>
#include <stdint.h>

// VarifoldKernel: out[b] = sum_{n,m} w1[b,n]*w2[b,m]*exp(-2*||p1-p2||^2)*exp(-f1.f2/2)
// Log-space: term = 2^( dot(A1[n], A2[m]) ) where the K=96-padded rows carry
//   A1 = [2*pos1, 0, feat1,            la1_hi, la1_lo, 1, 1, 0...]   (fp16)
//   A2 = [2*L*pos2, 0, -0.5*L*feat2,   1, 1, la2_hi, la2_lo, 0...]   (fp16)
//   la = clamp(log2(w) - 2*L*|pos|^2, >= -1000), hi/lo fp16 split, L = log2(e)
// => MFMA accumulator exits with dot + la1 + la2; epilogue = psum += exp2(acc).
// R8 = R6 (best measured: 88.4us) + ONE change: 4 independent psum
//      accumulators to break the 256-deep serial exp2->add dependency chain
//      (R7's only untested micro-change; its cooperative launch failed and is
//      abandoned — plain triple-dispatch restored).

typedef _Float16 f16;
typedef _Float16 v8h __attribute__((ext_vector_type(8)));
typedef _Float16 h4  __attribute__((ext_vector_type(4)));
typedef float    v4f __attribute__((ext_vector_type(4)));

#define L2E 1.4426950408889634f
#define BN 4096
#define KP 96    // padded K (halfs); row = 192 B

// ---------------- prep: fp32 -> fp16 U matrices (log terms folded into K-pad) -------
__global__ __launch_bounds__(256) void prep_kernel(
    const float* __restrict__ pos1, const float* __restrict__ feat1, const float* __restrict__ w1,
    const float* __restrict__ pos2, const float* __restrict__ feat2, const float* __restrict__ w2,
    f16* __restrict__ U1, f16* __restrict__ U2)
{
    int tid  = threadIdx.x;
    int ridx = blockIdx.x * 16 + (tid >> 4);   // 0..32767
    int c    = tid & 15;
    int side = ridx >> 14;                     // 0: side1, 1: side2
    int idx  = ridx & 16383;                   // b*4096 + row

    const float* feat = side ? feat2 : feat1;
    f16* U   = side ? U2 : U1;
    float fs = side ? -0.5f * L2E : 1.0f;

    // feat -> halfs 4..67 (c-th float4 -> h4 at 4+4c), coalesced
    float4 v = ((const float4*)feat)[idx * 16 + c];
    *(h4*)(U + (long)idx * KP + 4 + c * 4) =
        h4{(f16)(v.x * fs), (f16)(v.y * fs), (f16)(v.z * fs), (f16)(v.w * fs)};

    if (c == 0) {
        const float* pos = side ? pos2 : pos1;
        const float* w   = side ? w2   : w1;
        float ps  = side ? 2.0f * L2E : 2.0f;
        float p0 = pos[idx*3+0], p1 = pos[idx*3+1], p2 = pos[idx*3+2];
        // log-space row term, clamped so w==0 can't yield -inf (then lo would be NaN)
        float la = __builtin_amdgcn_logf(w[idx]) - 2.0f * L2E * (p0*p0 + p1*p1 + p2*p2);
        la = fmaxf(la, -1000.0f);
        f16   hi = (f16)la;
        f16   lo = (f16)(la - (float)hi);
        *(h4*)(U + (long)idx * KP) = h4{(f16)(p0*ps), (f16)(p1*ps), (f16)(p2*ps), (f16)0.0f};
        // k68..71: A-side carries {la1_hi, la1_lo, 1, 1}; B-side {1, 1, la2_hi, la2_lo}
        *(h4*)(U + (long)idx * KP + 68) =
            side ? h4{(f16)1.0f, (f16)1.0f, hi, lo}
                 : h4{hi, lo, (f16)1.0f, (f16)1.0f};
    } else if (c <= 6) {
        // k72..95 zero (6 x h4)
        *(h4*)(U + (long)idx * KP + 72 + (c - 1) * 4) =
            h4{(f16)0.0f, (f16)0.0f, (f16)0.0f, (f16)0.0f};
    }
}

// ---------------- main: barrier-free, register-persistent B stripe (R3/R6 core) -----
// Block = 4 waves. Wave w owns cols [stripe*256 + w*64, +64) for a 256-row chunk.
// B frags persist in registers; A frags loaded per 16-row tile with 1-tile prefetch.
// Epilogue: 4 independent accumulators, psN += exp2(acc[N][e]).
__global__ __launch_bounds__(256, 4) void varifold_kernel(
    const f16* __restrict__ U1, const f16* __restrict__ U2,
    float* __restrict__ pw)
{
    int tid = threadIdx.x, wave = tid >> 6, lane = tid & 63;
    int stripe = blockIdx.x, nchunk = blockIdx.y, b = blockIdx.z;
    int l15 = lane & 15, quad = lane >> 4;

    long colr = (long)b*BN + stripe*256 + wave*64;   // this wave's first col row-index
    long row0 = (long)b*BN + nchunk*256;             // this block's first row

    // --- persistent B fragments (registers for whole kernel) ---
    v8h bf[3][4];
    #pragma unroll
    for (int j = 0; j < 4; ++j) {
        const f16* r = U2 + (colr + j*16 + l15) * KP + quad*8;
        bf[0][j] = *(const v8h*)(r);
        bf[1][j] = *(const v8h*)(r + 32);
        bf[2][j] = *(const v8h*)(r + 64);
    }

    const f16* Ab = U1 + (row0 + l15) * KP + quad*8;  // A frag base (+16 rows/tile)
    v8h afc[3], afn[3];
    afc[0] = *(const v8h*)(Ab);
    afc[1] = *(const v8h*)(Ab + 32);
    afc[2] = *(const v8h*)(Ab + 64);

    float ps0 = 0.f, ps1 = 0.f, ps2 = 0.f, ps3 = 0.f;
    #pragma unroll 2
    for (int t = 0; t < 16; ++t) {
        // prefetch next tile's A fragments (clamped; last iter re-loads self)
        const f16* An = Ab + (t < 15 ? (t+1) : t) * 16 * KP;
        afn[0] = *(const v8h*)(An);
        afn[1] = *(const v8h*)(An + 32);
        afn[2] = *(const v8h*)(An + 64);

        v4f acc[4];
        #pragma unroll
        for (int j = 0; j < 4; ++j) acc[j] = v4f{0.f, 0.f, 0.f, 0.f};
        #pragma unroll
        for (int k = 0; k < 3; ++k)
            #pragma unroll
            for (int j = 0; j < 4; ++j)
                acc[j] = __builtin_amdgcn_mfma_f32_16x16x32_f16(afc[k], bf[k][j], acc[j], 0, 0, 0);

        // epilogue: accumulator already holds dot + la1 + la2.
        // 4 independent sums -> dependency chain is 4 adds/tile per stream.
        ps0 += __builtin_amdgcn_exp2f(acc[0][0]);
        ps0 += __builtin_amdgcn_exp2f(acc[0][1]);
        ps0 += __builtin_amdgcn_exp2f(acc[0][2]);
        ps0 += __builtin_amdgcn_exp2f(acc[0][3]);
        ps1 += __builtin_amdgcn_exp2f(acc[1][0]);
        ps1 += __builtin_amdgcn_exp2f(acc[1][1]);
        ps1 += __builtin_amdgcn_exp2f(acc[1][2]);
        ps1 += __builtin_amdgcn_exp2f(acc[1][3]);
        ps2 += __builtin_amdgcn_exp2f(acc[2][0]);
        ps2 += __builtin_amdgcn_exp2f(acc[2][1]);
        ps2 += __builtin_amdgcn_exp2f(acc[2][2]);
        ps2 += __builtin_amdgcn_exp2f(acc[2][3]);
        ps3 += __builtin_amdgcn_exp2f(acc[3][0]);
        ps3 += __builtin_amdgcn_exp2f(acc[3][1]);
        ps3 += __builtin_amdgcn_exp2f(acc[3][2]);
        ps3 += __builtin_amdgcn_exp2f(acc[3][3]);

        afc[0] = afn[0]; afc[1] = afn[1]; afc[2] = afn[2];
    }

    float psum = (ps0 + ps1) + (ps2 + ps3);

    // --- wave reduce -> one plain store per wave (no atomics, no LDS) ---
    #pragma unroll
    for (int off = 32; off > 0; off >>= 1) psum += __shfl_down(psum, off);
    if (lane == 0)
        pw[(((long)b*16 + nchunk)*16 + stripe)*4 + wave] = psum;
}

// ---------------- final: reduce 1024 partials per batch -> out[b] -------------------
__global__ __launch_bounds__(256) void reduce_kernel(
    const float* __restrict__ pw, float* __restrict__ out)
{
    __shared__ float sred[4];
    int b = blockIdx.x, tid = threadIdx.x;
    const float* p = pw + (long)b * 1024;
    float v = p[tid] + p[tid + 256] + p[tid + 512] + p[tid + 768];
    #pragma unroll
    for (int off = 32; off > 0; off >>= 1) v += __shfl_down(v, off);
    if ((tid & 63) == 0) sred[tid >> 6] = v;
    __syncthreads();
    if (tid == 0) out[b] = sred[0] + sred[1] + sred[2] + sred[3];
}

extern "C" void kernel_launch(void* const* d_in, const int* in_sizes, int n_in,
                              void* d_out, int out_size, void* d_ws, size_t ws_size,
                              hipStream_t stream) {
    const float* pos1  = (const float*)d_in[0];
    const float* feat1 = (const float*)d_in[1];
    const float* w1    = (const float*)d_in[2];
    const float* pos2  = (const float*)d_in[3];
    const float* feat2 = (const float*)d_in[4];
    const float* w2    = (const float*)d_in[5];
    float* out = (float*)d_out;

    // workspace layout (6,307,840 B)
    char* ws = (char*)d_ws;
    f16*   U1  = (f16*)(ws);                          // 3,145,728
    f16*   U2  = (f16*)(ws + 3145728);                // 3,145,728
    float* pw  = (float*)(ws + 6291456);              // 4096*4 = 16,384

    prep_kernel<<<2048, 256, 0, stream>>>(pos1, feat1, w1, pos2, feat2, w2, U1, U2);
    dim3 grid(16, 16, 4);  // (stripe, nchunk, b) — stripe fastest for A-row L2 locality
    varifold_kernel<<<grid, 256, 0, stream>>>(U1, U2, pw);
    reduce_kernel<<<4, 256, 0, stream>>>(pw, out);
}